// Round 2
// baseline (54373.798 us; speedup 1.0000x reference)
//
#include <hip/hip_runtime.h>
#include <hip/hip_bf16.h>

#define FEATURES 128
#define NEURONS  512
#define THETA    256
#define KCAT     896   // 512 (x) + 256 (s) + 128 (I)
#define TT       2048
#define BB       64

typedef unsigned int uint32;
using bf16 = __hip_bfloat16;

// ---------------------------------------------------------------------------
// Weight prep: bf16, laid out in EXACT wave load order so the scan kernel's
// weight stream is sequential dwordx4 per lane.
//
// Phase A (W_cat = [x:W_ih[:, :512] | s:W_hh | I:W_ih[:, 512:]], k-major):
//   wave w (0..15): kq = w>>2 (k-quarter of 224), jb = w&3 (j-block of 64)
//   WA[((w*28 + i)*64 + l)*8 + e] = W_cat[k = kq*224 + i*8 + e][j = jb*64 + l]
// Phase B:
//   wave w (0..15): nb = w>>1 (n-block of 64), kh = w&1 (k-half of 128)
//   WB[((w*16 + i)*64 + l)*8 + e] = W_out[n = nb*64 + l][k = kh*128 + i*8 + e]
// ---------------------------------------------------------------------------
__global__ void prep_kernel(const float* __restrict__ W_ih,
                            const float* __restrict__ W_hh,
                            const float* __restrict__ W_out,
                            bf16* __restrict__ WA,
                            bf16* __restrict__ WB)
{
    int e = blockIdx.x * blockDim.x + threadIdx.x;
    const int NA = 16 * 28 * 64 * 8;   // 229376
    const int NB = 16 * 16 * 64 * 8;   // 131072
    if (e < NA) {
        int ee = e & 7;
        int l  = (e >> 3) & 63;
        int q  = e >> 9;          // w*28 + i
        int w  = q / 28;
        int i  = q % 28;
        int kq = w >> 2, jb = w & 3;
        int j  = jb * 64 + l;
        int k  = kq * 224 + i * 8 + ee;
        float v;
        if (k < 512)      v = W_ih[j * 640 + k];
        else if (k < 768) v = W_hh[j * 256 + (k - 512)];
        else              v = W_ih[j * 640 + 512 + (k - 768)];
        WA[e] = __float2bfloat16(v);
    } else if (e < NA + NB) {
        int e2 = e - NA;
        int ee = e2 & 7;
        int l  = (e2 >> 3) & 63;
        int q  = e2 >> 9;         // w*16 + i
        int w  = q >> 4;
        int i  = q & 15;
        int nb = w >> 1, kh = w & 1;
        int n  = nb * 64 + l;
        int k  = kh * 128 + i * 8 + ee;
        WB[e2] = __float2bfloat16(W_out[n * 256 + k]);
    }
}

__device__ __forceinline__ float lo16(uint32 u) { return __uint_as_float(u << 16); }
__device__ __forceinline__ float hi16(uint32 u) { return __uint_as_float(u & 0xffff0000u); }

// LDS-only barrier: orders LDS traffic across the workgroup WITHOUT draining
// vmcnt — global weight/I loads stay in flight across phases. Legal because
// all cross-thread communication in this kernel goes through LDS; global
// reads are read-only data and the out[] store stream is never read back.
__device__ __forceinline__ void bar_lds()
{
    asm volatile("s_waitcnt lgkmcnt(0)" ::: "memory");
    __builtin_amdgcn_s_barrier();
    asm volatile("" ::: "memory");
}

__global__ __launch_bounds__(1024)
void scan_kernel(const float* __restrict__ I,
                 const float* __restrict__ b_ih, const float* __restrict__ b_hh,
                 const float* __restrict__ b_out, const float* __restrict__ A,
                 const uint4* __restrict__ WA4, const uint4* __restrict__ WB4,
                 float* __restrict__ out)
{
    __shared__ float4 act4[KCAT / 4];     // [x 0:512 | s 512:768 | I 768:896]
    __shared__ float  part[1024];         // phase-A partials; reused as phase-B partials
    __shared__ float4 sbuf4[THETA / 4];
    __shared__ float  bsum[THETA];
    __shared__ float  bo[NEURONS];
    __shared__ float  Av[NEURONS];

    float* act  = (float*)act4;
    float* sbuf = (float*)sbuf4;

    const int tid = threadIdx.x;
    const int b   = blockIdx.x;
    const int l   = tid & 63;
    const int w   = tid >> 6;
    const int kq  = w >> 2;   // phase A k-quarter
    const int kh  = w & 1;    // phase B k-half

    if (tid < THETA)   bsum[tid] = b_ih[tid] + b_hh[tid];
    if (tid < NEURONS) { bo[tid] = b_out[tid]; Av[tid] = A[tid]; }
    if (tid < NEURONS + THETA) act[tid] = 0.0f;   // x = 0, s = 0
    const size_t iBase   = (size_t)b * TT * FEATURES;
    const size_t outBase = (size_t)b * TT * NEURONS;
    if (tid < FEATURES) act[NEURONS + THETA + tid] = I[iBase + tid];  // I(0)
    bar_lds();

    const int waBase = w * 28 * 64 + l;
    const int wbBase = w * 16 * 64 + l;

    for (int t = 0; t < TT; ++t) {
        // ---- phase A: pre[j] partial over k-quarter (rolling 8-deep prefetch) ----
        uint4 wa[8];
        #pragma unroll
        for (int p = 0; p < 8; ++p) wa[p] = WA4[waBase + p * 64];
        float acc0 = 0.f, acc1 = 0.f;
        #pragma unroll
        for (int i = 0; i < 28; ++i) {
            uint4 wv = wa[i & 7];
            if (i + 8 < 28) wa[i & 7] = WA4[waBase + (i + 8) * 64];
            float4 a0 = act4[kq * 56 + i * 2];       // wave-uniform -> LDS broadcast
            float4 a1 = act4[kq * 56 + i * 2 + 1];
            acc0 = fmaf(a0.x, lo16(wv.x), acc0); acc1 = fmaf(a0.y, hi16(wv.x), acc1);
            acc0 = fmaf(a0.z, lo16(wv.y), acc0); acc1 = fmaf(a0.w, hi16(wv.y), acc1);
            acc0 = fmaf(a1.x, lo16(wv.z), acc0); acc1 = fmaf(a1.y, hi16(wv.z), acc1);
            acc0 = fmaf(a1.z, lo16(wv.w), acc0); acc1 = fmaf(a1.w, hi16(wv.w), acc1);
        }
        // pre-issue phase-B loads BEFORE the two barriers: port stays busy
        uint4 wb[8];
        #pragma unroll
        for (int p = 0; p < 8; ++p) wb[p] = WB4[wbBase + p * 64];
        part[tid] = acc0 + acc1;
        bar_lds();   // 1

        if (tid < THETA) {
            float pre = part[tid] + part[tid + 256] + part[tid + 512] + part[tid + 768]
                      + bsum[tid];
            float s = tanhf(pre);
            sbuf[tid] = s;
            act[NEURONS + tid] = s;   // s state for step t+1
        }
        bar_lds();   // 2

        // ---- phase B: f[n] partial over k-half ----
        float accB0 = 0.f, accB1 = 0.f;
        #pragma unroll
        for (int i = 0; i < 16; ++i) {
            uint4 wv = wb[i & 7];
            if (i + 8 < 16) wb[i & 7] = WB4[wbBase + (i + 8) * 64];
            float4 s0 = sbuf4[kh * 32 + i * 2];
            float4 s1 = sbuf4[kh * 32 + i * 2 + 1];
            accB0 = fmaf(s0.x, lo16(wv.x), accB0); accB1 = fmaf(s0.y, hi16(wv.x), accB1);
            accB0 = fmaf(s0.z, lo16(wv.y), accB0); accB1 = fmaf(s0.w, hi16(wv.y), accB1);
            accB0 = fmaf(s1.x, lo16(wv.z), accB0); accB1 = fmaf(s1.y, hi16(wv.z), accB1);
            accB0 = fmaf(s1.z, lo16(wv.w), accB0); accB1 = fmaf(s1.w, hi16(wv.w), accB1);
        }
        part[tid] = accB0 + accB1;   // reuse as pb[]
        // prefetch I(t+1) while pb settles
        int tn = (t + 1 < TT) ? (t + 1) : t;
        float iNext = (tid < FEATURES) ? I[iBase + (size_t)tn * FEATURES + tid] : 0.f;
        bar_lds();   // 3

        if (tid < NEURONS) {
            int idx = ((tid >> 6) * 128) + (tid & 63);   // pb partial location
            float f = part[idx] + part[idx + 64] + bo[tid];
            f = fmaxf(f, 0.f);
            float xo = act[tid];
            float xn = (xo + 0.1f * f * Av[tid]) / (1.1f + 0.1f * f);
            act[tid] = xn;            // x state for step t+1
            out[outBase + (size_t)t * NEURONS + tid] = xn;
        }
        if (tid < FEATURES) act[NEURONS + THETA + tid] = iNext;
        bar_lds();   // 4 (loop top: act x/I writes visible to next phase A)
    }
}

extern "C" void kernel_launch(void* const* d_in, const int* in_sizes, int n_in,
                              void* d_out, int out_size, void* d_ws, size_t ws_size,
                              hipStream_t stream)
{
    const float* I     = (const float*)d_in[0];
    const float* W_ih  = (const float*)d_in[1];
    const float* W_hh  = (const float*)d_in[2];
    const float* b_ih  = (const float*)d_in[3];
    const float* b_hh  = (const float*)d_in[4];
    const float* W_out = (const float*)d_in[5];
    const float* b_out = (const float*)d_in[6];
    const float* A     = (const float*)d_in[7];

    bf16* WA = (bf16*)d_ws;                                    // 229376 bf16
    bf16* WB = (bf16*)((char*)d_ws + 229376 * sizeof(bf16));   // 131072 bf16

    const int total = 229376 + 131072;
    prep_kernel<<<(total + 1023) / 1024, 1024, 0, stream>>>(W_ih, W_hh, W_out, WA, WB);
    scan_kernel<<<BB, 1024, 0, stream>>>(I, b_ih, b_hh, b_out, A,
                                         (const uint4*)WA, (const uint4*)WB,
                                         (float*)d_out);
}

// Round 3
// 5680.818 us; speedup vs baseline: 9.5715x; 9.5715x over previous
//
#include <hip/hip_runtime.h>
#include <hip/hip_bf16.h>

#define TT 2048
typedef unsigned int uint32;

// ---- d_ws layout (floats/uints) ----
// WREG : uint32 [4][88][512]            offset 0        (720896 B)
// exA  : float  [2][64][4][256]         offset 180224   (524288 B)
// flags: uint32 [64*16] (64B padded)    offset 311296+   (4096 B)
#define WREG_N   (4 * 88 * 512)          // 180224
#define EXA_OFF  WREG_N
#define EXA_N    (2 * 64 * 4 * 256)      // 131072
#define FLAG_OFF (EXA_OFF + EXA_N)
#define FLAG_N   (64 * 16)

__device__ __forceinline__ float lo16(uint32 u) { return __uint_as_float(u << 16); }
__device__ __forceinline__ float hi16(uint32 u) { return __uint_as_float(u & 0xffff0000u); }

__device__ __forceinline__ uint32 packbf(float lo, float hi)
{
    __hip_bfloat16 a = __float2bfloat16(lo), b = __float2bfloat16(hi);
    unsigned short ua = *reinterpret_cast<unsigned short*>(&a);
    unsigned short ub = *reinterpret_cast<unsigned short*>(&b);
    return (uint32)ua | ((uint32)ub << 16);
}

// cat k-slice for gang member g: [x[128g..+128) | s[64g..+64) | I[32g..+32)]
__device__ __forceinline__ float getA(const float* W_ih, const float* W_hh,
                                      int g, int j, int k)
{
    if (k < 128) return W_ih[j * 640 + 128 * g + k];
    if (k < 192) return W_hh[j * 256 + 64 * g + (k - 128)];
    return W_ih[j * 640 + 512 + 32 * g + (k - 192)];
}

__global__ void prep_kernel(const float* __restrict__ W_ih,
                            const float* __restrict__ W_hh,
                            const float* __restrict__ W_out,
                            uint32* __restrict__ WREG,
                            uint32* __restrict__ flags)
{
    int idx = blockIdx.x * blockDim.x + threadIdx.x;
    if (idx < WREG_N) {
        int tid = idx & 511;
        int q   = idx >> 9;      // g*88 + i
        int g   = q / 88;
        int i   = q % 88;
        float lo, hi;
        if (i < 56) {            // phase-A weights: thread = (j, h)
            int j = tid & 255, h = tid >> 8;
            int k0 = 2 * (56 * h + i);
            lo = getA(W_ih, W_hh, g, j, k0);
            hi = getA(W_ih, W_hh, g, j, k0 + 1);
        } else {                 // phase-B weights: thread = (n, h4)
            int n = tid & 127, h4 = tid >> 7;
            int ii = i - 56;
            int k0 = 64 * h4 + 2 * ii;
            int gn = 128 * g + n;
            lo = W_out[gn * 256 + k0];
            hi = W_out[gn * 256 + k0 + 1];
        }
        WREG[idx] = packbf(lo, hi);
    } else if (idx < WREG_N + FLAG_N) {
        flags[idx - WREG_N] = 0;
    }
}

__global__ __launch_bounds__(512)
void scan_kernel(const float* __restrict__ I,
                 const float* __restrict__ b_ih, const float* __restrict__ b_hh,
                 const float* __restrict__ b_out, const float* __restrict__ A,
                 const uint32* __restrict__ WREG,
                 float* exA, uint32* flags,
                 float* __restrict__ out)
{
    __shared__ float aloc[224];   // [x_q 0:128 | s_q 128:192 | I_q 192:224]
    __shared__ float sful[256];   // full s (redundant per WG)
    __shared__ float part[512];

    const int tid = threadIdx.x;
    const int bid = blockIdx.x;
    const int b   = bid >> 2;     // batch element
    const int g   = bid & 3;      // gang member

    // ---- weights -> VGPR (static-indexed, fully unrolled) ----
    uint32 wA[56], wB[32];
    const uint32* wsrc = WREG + (g * 88) * 512 + tid;
    #pragma unroll
    for (int i = 0; i < 56; ++i) wA[i] = wsrc[i * 512];
    #pragma unroll
    for (int i = 0; i < 32; ++i) wB[i] = wsrc[(56 + i) * 512];

    const int j  = tid & 255;     // phase-A output row
    const int h  = tid >> 8;      // phase-A k-half (wave-uniform)
    const int h4 = tid >> 7;      // phase-B k-quarter (wave-uniform)

    const float bs   = (tid < 256) ? (b_ih[j] + b_hh[j]) : 0.f;
    const float bo_r = (tid < 128) ? b_out[128 * g + tid] : 0.f;
    const float Av_r = (tid < 128) ? A[128 * g + tid] : 0.f;

    if (tid < 224) aloc[tid] = 0.f;      // x_q = 0, s_q = 0
    if (tid < 256) sful[tid] = 0.f;
    const size_t iBase   = (size_t)b * TT * 128 + 32 * g;
    const size_t outBase = (size_t)b * TT * 512 + 128 * g;
    if (tid < 32) aloc[192 + tid] = I[iBase + tid];   // I(0) quarter
    uint32* flagB = flags + b * 16;
    __syncthreads();

    const float4* aloc4 = (const float4*)aloc;
    const float4* s4    = (const float4*)sful;

    for (int t = 0; t < TT; ++t) {
        // ---- phase A: partial pre[j] over this WG's 224-k slice ----
        float a0 = 0.f, a1 = 0.f;
        #pragma unroll
        for (int i = 0; i < 28; ++i) {
            float4 av = aloc4[28 * h + i];          // wave-uniform LDS broadcast
            uint32 w0 = wA[2 * i], w1 = wA[2 * i + 1];
            a0 = fmaf(av.x, lo16(w0), a0);
            a1 = fmaf(av.y, hi16(w0), a1);
            a0 = fmaf(av.z, lo16(w1), a0);
            a1 = fmaf(av.w, hi16(w1), a1);
        }
        part[tid] = a0 + a1;
        __syncthreads();                            // (1)

        const int par = t & 1;
        float* exbuf = exA + (size_t)(par * 64 + b) * 4 * 256;
        float p = 0.f;
        if (tid < 256) {
            p = part[tid] + part[tid + 256];        // WG partial for row j
            __hip_atomic_store(exbuf + g * 256 + tid, p,
                               __ATOMIC_RELAXED, __HIP_MEMORY_SCOPE_AGENT);
        }
        asm volatile("s_waitcnt vmcnt(0)" ::: "memory");  // stores IC-visible
        __syncthreads();                            // (2) all waves' stores done

        if (tid == 0) {
            __hip_atomic_fetch_add(flagB, 1u, __ATOMIC_RELAXED, __HIP_MEMORY_SCOPE_AGENT);
            const uint32 tgt = 4u * (uint32)(t + 1);
            while (__hip_atomic_load(flagB, __ATOMIC_RELAXED, __HIP_MEMORY_SCOPE_AGENT) < tgt)
                __builtin_amdgcn_s_sleep(1);
        }
        __syncthreads();                            // (3) flag reached -> all partials visible

        float iv = 0.f;
        if (tid < 256) {
            float pre = p + bs;
            #pragma unroll
            for (int gg = 1; gg < 4; ++gg) {
                int go = (g + gg) & 3;
                pre += __hip_atomic_load(exbuf + go * 256 + tid,
                                         __ATOMIC_RELAXED, __HIP_MEMORY_SCOPE_AGENT);
            }
            float sn = tanhf(pre);
            sful[tid] = sn;                         // full s (local copy)
            int d = tid - 64 * g;
            if (d >= 0 && d < 64) aloc[128 + d] = sn;   // own s-quarter for next A
        }
        if (tid < 32) {                             // prefetch I(t+1), hides under phase B
            int tl = (t + 1 < TT) ? (t + 1) : t;
            iv = I[iBase + (size_t)tl * 128 + tid];
        }
        __syncthreads();                            // (4)

        // ---- phase B: partial f[n] over this WG's n-quarter, k-quarter per thread ----
        float c0 = 0.f, c1 = 0.f;
        #pragma unroll
        for (int i = 0; i < 16; ++i) {
            float4 sv = s4[16 * h4 + i];            // wave-uniform LDS broadcast
            uint32 w0 = wB[2 * i], w1 = wB[2 * i + 1];
            c0 = fmaf(sv.x, lo16(w0), c0);
            c1 = fmaf(sv.y, hi16(w0), c1);
            c0 = fmaf(sv.z, lo16(w1), c0);
            c1 = fmaf(sv.w, hi16(w1), c1);
        }
        part[tid] = c0 + c1;
        __syncthreads();                            // (5)

        if (tid < 128) {
            float f = part[tid] + part[tid + 128] + part[tid + 256] + part[tid + 384] + bo_r;
            f = fmaxf(f, 0.f);
            float xo = aloc[tid];
            float xn = (xo + 0.1f * f * Av_r) / (1.1f + 0.1f * f);
            aloc[tid] = xn;                         // own x-quarter for next A
            out[outBase + (size_t)t * 512 + tid] = xn;
        }
        if (tid < 32) aloc[192 + tid] = iv;         // stage I(t+1)
        __syncthreads();                            // (6)
    }
}

extern "C" void kernel_launch(void* const* d_in, const int* in_sizes, int n_in,
                              void* d_out, int out_size, void* d_ws, size_t ws_size,
                              hipStream_t stream)
{
    const float* I     = (const float*)d_in[0];
    const float* W_ih  = (const float*)d_in[1];
    const float* W_hh  = (const float*)d_in[2];
    const float* b_ih  = (const float*)d_in[3];
    const float* b_hh  = (const float*)d_in[4];
    const float* W_out = (const float*)d_in[5];
    const float* b_out = (const float*)d_in[6];
    const float* A     = (const float*)d_in[7];

    uint32* WREG  = (uint32*)d_ws;
    float*  exA   = (float*)d_ws + EXA_OFF;
    uint32* flags = (uint32*)d_ws + FLAG_OFF;

    const int total = WREG_N + FLAG_N;
    prep_kernel<<<(total + 1023) / 1024, 1024, 0, stream>>>(W_ih, W_hh, W_out, WREG, flags);
    scan_kernel<<<256, 512, 0, stream>>>(I, b_ih, b_hh, b_out, A,
                                         WREG, exA, flags, (float*)d_out);
}

// Round 4
// 5488.467 us; speedup vs baseline: 9.9069x; 1.0350x over previous
//
#include <hip/hip_runtime.h>
#include <hip/hip_bf16.h>

#define TT 2048
typedef unsigned int uint32;

// ---- d_ws layout (dwords) ----
// WREG : uint32 [4][88][512]        offset 0         (720896 B)
// exA  : float  [2][64][4][256]     offset WREG_N    (524288 B)
// flags: uint32 [64][16]            offset FLAG_OFF  (4096 B; 16B line per gang, 64B padded)
#define WREG_N   (4 * 88 * 512)          // 180224
#define EXA_OFF  WREG_N
#define EXA_N    (2 * 64 * 4 * 256)      // 131072
#define FLAG_OFF (EXA_OFF + EXA_N)
#define FLAG_N   (64 * 16)

__device__ __forceinline__ float lo16(uint32 u) { return __uint_as_float(u << 16); }
__device__ __forceinline__ float hi16(uint32 u) { return __uint_as_float(u & 0xffff0000u); }

__device__ __forceinline__ uint32 packbf(float lo, float hi)
{
    __hip_bfloat16 a = __float2bfloat16(lo), b = __float2bfloat16(hi);
    unsigned short ua = *reinterpret_cast<unsigned short*>(&a);
    unsigned short ub = *reinterpret_cast<unsigned short*>(&b);
    return (uint32)ua | ((uint32)ub << 16);
}

// cat k-slice for gang member g: [x[128g..+128) | s[64g..+64) | I[32g..+32)]
__device__ __forceinline__ float getA(const float* W_ih, const float* W_hh,
                                      int g, int j, int k)
{
    if (k < 128) return W_ih[j * 640 + 128 * g + k];
    if (k < 192) return W_hh[j * 256 + 64 * g + (k - 128)];
    return W_ih[j * 640 + 512 + 32 * g + (k - 192)];
}

__global__ void prep_kernel(const float* __restrict__ W_ih,
                            const float* __restrict__ W_hh,
                            const float* __restrict__ W_out,
                            uint32* __restrict__ WREG,
                            uint32* __restrict__ flags)
{
    int idx = blockIdx.x * blockDim.x + threadIdx.x;
    if (idx < WREG_N) {
        int tid = idx & 511;
        int q   = idx >> 9;      // g*88 + i
        int g   = q / 88;
        int i   = q % 88;
        float lo, hi;
        if (i < 56) {            // phase-A weights: thread = (j, h)
            int j = tid & 255, h = tid >> 8;
            int k0 = 2 * (56 * h + i);
            lo = getA(W_ih, W_hh, g, j, k0);
            hi = getA(W_ih, W_hh, g, j, k0 + 1);
        } else {                 // phase-B weights: thread = (n, h4)
            int n = tid & 127, h4 = tid >> 7;
            int ii = i - 56;
            int k0 = 64 * h4 + 2 * ii;
            int gn = 128 * g + n;
            lo = W_out[gn * 256 + k0];
            hi = W_out[gn * 256 + k0 + 1];
        }
        WREG[idx] = packbf(lo, hi);
    } else if (idx < WREG_N + FLAG_N) {
        flags[idx - WREG_N] = 0;
    }
}

// LDS-only barrier: does NOT drain vmcnt (global ops stay in flight).
__device__ __forceinline__ void bar_lds()
{
    asm volatile("s_waitcnt lgkmcnt(0)" ::: "memory");
    __builtin_amdgcn_s_barrier();
    asm volatile("" ::: "memory");
}

__global__ __launch_bounds__(512)
void scan_kernel(const float* __restrict__ I,
                 const float* __restrict__ b_ih, const float* __restrict__ b_hh,
                 const float* __restrict__ b_out, const float* __restrict__ A,
                 const uint32* __restrict__ WREG,
                 float* exA, uint32* flags,
                 float* __restrict__ out)
{
    __shared__ float aloc[224];   // [x_q 0:128 | s_q 128:192 | I_q 192:224]
    __shared__ float sful[256];   // full s (redundant per WG)
    __shared__ float part[512];

    const int tid = threadIdx.x;
    const int bid = blockIdx.x;
    const int b   = bid >> 2;     // batch element
    const int g   = bid & 3;      // gang member

    // ---- weights -> VGPR (static-indexed, fully unrolled) ----
    uint32 wA[56], wB[32];
    const uint32* wsrc = WREG + (g * 88) * 512 + tid;
    #pragma unroll
    for (int i = 0; i < 56; ++i) wA[i] = wsrc[i * 512];
    #pragma unroll
    for (int i = 0; i < 32; ++i) wB[i] = wsrc[(56 + i) * 512];

    const int j  = tid & 255;     // phase-A output row
    const int h  = tid >> 8;      // phase-A k-half (wave-uniform)
    const int h4 = tid >> 7;      // phase-B k-quarter (wave-uniform)

    const float bs   = (tid < 256) ? (b_ih[j] + b_hh[j]) : 0.f;
    const float bo_r = (tid < 128) ? b_out[128 * g + tid] : 0.f;
    const float Av_r = (tid < 128) ? A[128 * g + tid] : 0.f;

    if (tid < 224) aloc[tid] = 0.f;      // x_q = 0, s_q = 0, I staged below
    const size_t iBase   = (size_t)b * TT * 128 + 32 * g;
    const size_t outBase = (size_t)b * TT * 512 + 128 * g;
    if (tid < 32) aloc[192 + tid] = I[iBase + tid];   // I(0) quarter
    uint32* flagB = flags + b * 16;
    __syncthreads();

    const float4* aloc4 = (const float4*)aloc;
    const float4* s4    = (const float4*)sful;

    for (int t = 0; t < TT; ++t) {
        // issue I(t+1) prefetch early; latency hides under phase A + sync
        float iv = 0.f;
        if (tid < 32) {
            int tl = (t + 1 < TT) ? (t + 1) : t;
            iv = I[iBase + (size_t)tl * 128 + tid];
        }

        // ---- phase A: partial pre[j] over this WG's 224-k slice ----
        float a0 = 0.f, a1 = 0.f;
        #pragma unroll
        for (int i = 0; i < 28; ++i) {
            float4 av = aloc4[28 * h + i];          // wave-uniform LDS broadcast
            uint32 w0 = wA[2 * i], w1 = wA[2 * i + 1];
            a0 = fmaf(av.x, lo16(w0), a0);
            a1 = fmaf(av.y, hi16(w0), a1);
            a0 = fmaf(av.z, lo16(w1), a0);
            a1 = fmaf(av.w, hi16(w1), a1);
        }
        part[tid] = a0 + a1;
        bar_lds();                                  // (1) partials visible

        const int par = t & 1;
        float* exbuf = exA + (size_t)(par * 64 + b) * 4 * 256;
        float p = 0.f;
        if (tid < 256) {
            p = part[tid] + part[tid + 256];        // WG partial for row j
            __hip_atomic_store(exbuf + g * 256 + tid, p,
                               __ATOMIC_RELAXED, __HIP_MEMORY_SCOPE_AGENT);
        }
        asm volatile("s_waitcnt vmcnt(0)" ::: "memory");  // this wave's stores at IC
        bar_lds();                                  // (2) ALL waves drained

        if (tid == 0)                               // plain store, no RMW
            __hip_atomic_store(flagB + g, (uint32)(t + 1),
                               __ATOMIC_RELAXED, __HIP_MEMORY_SCOPE_AGENT);

        if (tid < 256) {
            // every data-carrying thread polls; proceeds as soon as ready
            const uint32 tgt = (uint32)(t + 1);
            for (;;) {
                uint32 f0 = __hip_atomic_load(flagB + 0, __ATOMIC_RELAXED, __HIP_MEMORY_SCOPE_AGENT);
                uint32 f1 = __hip_atomic_load(flagB + 1, __ATOMIC_RELAXED, __HIP_MEMORY_SCOPE_AGENT);
                uint32 f2 = __hip_atomic_load(flagB + 2, __ATOMIC_RELAXED, __HIP_MEMORY_SCOPE_AGENT);
                uint32 f3 = __hip_atomic_load(flagB + 3, __ATOMIC_RELAXED, __HIP_MEMORY_SCOPE_AGENT);
                if (f0 >= tgt && f1 >= tgt && f2 >= tgt && f3 >= tgt) break;
                __builtin_amdgcn_s_sleep(1);
            }
            float pre = p + bs;
            #pragma unroll
            for (int gg = 1; gg < 4; ++gg) {
                int go = (g + gg) & 3;
                pre += __hip_atomic_load(exbuf + go * 256 + tid,
                                         __ATOMIC_RELAXED, __HIP_MEMORY_SCOPE_AGENT);
            }
            // tanh(x) = 1 - 2/(exp(2x)+1): exact identity, branch-free
            float e  = __expf(2.f * pre);
            float sn = 1.f - 2.f / (e + 1.f);
            sful[tid] = sn;                         // full s (local copy)
            int d = tid - 64 * g;
            if (d >= 0 && d < 64) aloc[128 + d] = sn;   // own s-quarter for next A
        }
        bar_lds();                                  // (3) s ready

        // ---- phase B: partial f[n] over this WG's n-quarter, k-quarter/thread ----
        float c0 = 0.f, c1 = 0.f;
        #pragma unroll
        for (int i = 0; i < 16; ++i) {
            float4 sv = s4[16 * h4 + i];            // wave-uniform LDS broadcast
            uint32 w0 = wB[2 * i], w1 = wB[2 * i + 1];
            c0 = fmaf(sv.x, lo16(w0), c0);
            c1 = fmaf(sv.y, hi16(w0), c1);
            c0 = fmaf(sv.z, lo16(w1), c0);
            c1 = fmaf(sv.w, hi16(w1), c1);
        }
        part[tid] = c0 + c1;
        bar_lds();                                  // (4) B partials visible

        if (tid < 128) {
            float f = part[tid] + part[tid + 128] + part[tid + 256] + part[tid + 384] + bo_r;
            f = fmaxf(f, 0.f);
            float xo = aloc[tid];
            float xn = (xo + 0.1f * f * Av_r) / (1.1f + 0.1f * f);
            aloc[tid] = xn;                         // own x-quarter for next A
            out[outBase + (size_t)t * 512 + tid] = xn;
        }
        if (tid < 32) aloc[192 + tid] = iv;         // stage I(t+1)
        bar_lds();                                  // (5) state ready for next A
    }
}

extern "C" void kernel_launch(void* const* d_in, const int* in_sizes, int n_in,
                              void* d_out, int out_size, void* d_ws, size_t ws_size,
                              hipStream_t stream)
{
    const float* I     = (const float*)d_in[0];
    const float* W_ih  = (const float*)d_in[1];
    const float* W_hh  = (const float*)d_in[2];
    const float* b_ih  = (const float*)d_in[3];
    const float* b_hh  = (const float*)d_in[4];
    const float* W_out = (const float*)d_in[5];
    const float* b_out = (const float*)d_in[6];
    const float* A     = (const float*)d_in[7];

    uint32* WREG  = (uint32*)d_ws;
    float*  exA   = (float*)d_ws + EXA_OFF;
    uint32* flags = (uint32*)d_ws + FLAG_OFF;

    const int total = WREG_N + FLAG_N;
    prep_kernel<<<(total + 1023) / 1024, 1024, 0, stream>>>(W_ih, W_hh, W_out, WREG, flags);
    scan_kernel<<<256, 512, 0, stream>>>(I, b_ih, b_hh, b_out, A,
                                         WREG, exA, flags, (float*)d_out);
}

// Round 5
// 4293.796 us; speedup vs baseline: 12.6633x; 1.2782x over previous
//
#include <hip/hip_runtime.h>
#include <hip/hip_bf16.h>

#define TT 2048
typedef unsigned int uint32;
typedef unsigned long long uint64;

// ---- d_ws layout ----
// WREG : uint32 [4][88][512]                  offset 0        (720896 B)
// exA  : uint64 [2][64][4][256]  {f32,tag}    offset 720896 B (2097152 B)
#define WREG_N   (4 * 88 * 512)          // 180224 dwords
#define EXA_N    (2 * 64 * 4 * 256)      // 131072 qwords

__device__ __forceinline__ float lo16(uint32 u) { return __uint_as_float(u << 16); }
__device__ __forceinline__ float hi16(uint32 u) { return __uint_as_float(u & 0xffff0000u); }

__device__ __forceinline__ uint32 packbf(float lo, float hi)
{
    __hip_bfloat16 a = __float2bfloat16(lo), b = __float2bfloat16(hi);
    unsigned short ua = *reinterpret_cast<unsigned short*>(&a);
    unsigned short ub = *reinterpret_cast<unsigned short*>(&b);
    return (uint32)ua | ((uint32)ub << 16);
}

// cat k-slice for gang member g: [x[128g..+128) | s[64g..+64) | I[32g..+32)]
__device__ __forceinline__ float getA(const float* W_ih, const float* W_hh,
                                      int g, int j, int k)
{
    if (k < 128) return W_ih[j * 640 + 128 * g + k];
    if (k < 192) return W_hh[j * 256 + 64 * g + (k - 128)];
    return W_ih[j * 640 + 512 + 32 * g + (k - 192)];
}

__global__ void prep_kernel(const float* __restrict__ W_ih,
                            const float* __restrict__ W_hh,
                            const float* __restrict__ W_out,
                            uint32* __restrict__ WREG,
                            uint64* __restrict__ exA)
{
    int idx = blockIdx.x * blockDim.x + threadIdx.x;
    if (idx < WREG_N) {
        int tid = idx & 511;
        int q   = idx >> 9;      // g*88 + i
        int g   = q / 88;
        int i   = q % 88;
        float lo, hi;
        if (i < 56) {            // phase-A weights: thread = (j, h)
            int j = tid & 255, h = tid >> 8;
            int k0 = 2 * (56 * h + i);
            lo = getA(W_ih, W_hh, g, j, k0);
            hi = getA(W_ih, W_hh, g, j, k0 + 1);
        } else {                 // phase-B weights: thread = (n, h4)
            int n = tid & 127, h4 = tid >> 7;
            int ii = i - 56;
            int k0 = 64 * h4 + 2 * ii;
            int gn = 128 * g + n;
            lo = W_out[gn * 256 + k0];
            hi = W_out[gn * 256 + k0 + 1];
        }
        WREG[idx] = packbf(lo, hi);
    } else if (idx < WREG_N + EXA_N) {
        exA[idx - WREG_N] = 0ULL;   // tags must start at 0 (ws is 0xAA-poisoned)
    }
}

// LDS-only barrier: does NOT drain vmcnt (global ops stay in flight).
__device__ __forceinline__ void bar_lds()
{
    asm volatile("s_waitcnt lgkmcnt(0)" ::: "memory");
    __builtin_amdgcn_s_barrier();
    asm volatile("" ::: "memory");
}

__global__ __launch_bounds__(512)
void scan_kernel(const float* __restrict__ I,
                 const float* __restrict__ b_ih, const float* __restrict__ b_hh,
                 const float* __restrict__ b_out, const float* __restrict__ A,
                 const uint32* __restrict__ WREG,
                 uint64* exA,
                 float* __restrict__ out)
{
    __shared__ float aloc[224];   // [x_q 0:128 | s_q 128:192 | I_q 192:224]
    __shared__ float sful[256];   // full s (redundant per WG)
    __shared__ float part[512];

    const int tid = threadIdx.x;
    const int bid = blockIdx.x;
    const int b   = bid & 63;     // batch element
    const int g   = bid >> 6;     // gang member (blocks b, b+64, b+128, b+192
                                  //  -> same XCD under round-robin %8; correctness-neutral)

    // ---- weights -> VGPR (static-indexed, fully unrolled) ----
    uint32 wA[56], wB[32];
    const uint32* wsrc = WREG + (g * 88) * 512 + tid;
    #pragma unroll
    for (int i = 0; i < 56; ++i) wA[i] = wsrc[i * 512];
    #pragma unroll
    for (int i = 0; i < 32; ++i) wB[i] = wsrc[(56 + i) * 512];

    const int j  = tid & 255;     // phase-A output row
    const int h  = tid >> 8;      // phase-A k-half (wave-uniform)
    const int h4 = tid >> 7;      // phase-B k-quarter (wave-uniform)

    const float bs   = (tid < 256) ? (b_ih[j] + b_hh[j]) : 0.f;
    const float bo_r = (tid < 128) ? b_out[128 * g + tid] : 0.f;
    const float Av_r = (tid < 128) ? A[128 * g + tid] : 0.f;

    if (tid < 224) aloc[tid] = 0.f;      // x_q = 0, s_q = 0, I staged below
    const size_t iBase   = (size_t)b * TT * 128 + 32 * g;
    const size_t outBase = (size_t)b * TT * 512 + 128 * g;
    if (tid < 32) aloc[192 + tid] = I[iBase + tid];   // I(0) quarter
    __syncthreads();

    const float4* aloc4 = (const float4*)aloc;
    const float4* s4    = (const float4*)sful;

    for (int t = 0; t < TT; ++t) {
        // issue I(t+1) prefetch early; latency hides under phase A + sync
        float iv = 0.f;
        if (tid < 32) {
            int tl = (t + 1 < TT) ? (t + 1) : t;
            iv = I[iBase + (size_t)tl * 128 + tid];
        }

        // ---- phase A: partial pre[j] over this WG's 224-k slice ----
        float a0 = 0.f, a1 = 0.f;
        #pragma unroll
        for (int i = 0; i < 28; ++i) {
            float4 av = aloc4[28 * h + i];          // wave-uniform LDS broadcast
            uint32 w0 = wA[2 * i], w1 = wA[2 * i + 1];
            a0 = fmaf(av.x, lo16(w0), a0);
            a1 = fmaf(av.y, hi16(w0), a1);
            a0 = fmaf(av.z, lo16(w1), a0);
            a1 = fmaf(av.w, hi16(w1), a1);
        }
        part[tid] = a0 + a1;
        bar_lds();                                  // (1) partials visible in LDS

        const int par = t & 1;
        uint64* ex = exA + (size_t)(par * 64 + b) * (4 * 256);
        const uint32 tgt = (uint32)(t + 1);

        if (tid < 256) {
            // single 8B store: payload + tag travel together (no drain, no flag)
            float p = part[tid] + part[tid + 256];
            uint64 u = ((uint64)tgt << 32) | (uint64)__float_as_uint(p);
            __hip_atomic_store(ex + g * 256 + tid, u,
                               __ATOMIC_RELAXED, __HIP_MEMORY_SCOPE_AGENT);

            // poll peers' payload words directly; fixed-order sum for determinism
            float v0 = 0.f, v1 = 0.f, v2 = 0.f;
            uint32 got = 0;
            const int g1 = (g + 1) & 3, g2 = (g + 2) & 3, g3 = (g + 3) & 3;
            do {
                if (!(got & 1u)) {
                    uint64 u1 = __hip_atomic_load(ex + g1 * 256 + tid,
                                                  __ATOMIC_RELAXED, __HIP_MEMORY_SCOPE_AGENT);
                    if ((uint32)(u1 >> 32) == tgt) { v0 = __uint_as_float((uint32)u1); got |= 1u; }
                }
                if (!(got & 2u)) {
                    uint64 u2 = __hip_atomic_load(ex + g2 * 256 + tid,
                                                  __ATOMIC_RELAXED, __HIP_MEMORY_SCOPE_AGENT);
                    if ((uint32)(u2 >> 32) == tgt) { v1 = __uint_as_float((uint32)u2); got |= 2u; }
                }
                if (!(got & 4u)) {
                    uint64 u3 = __hip_atomic_load(ex + g3 * 256 + tid,
                                                  __ATOMIC_RELAXED, __HIP_MEMORY_SCOPE_AGENT);
                    if ((uint32)(u3 >> 32) == tgt) { v2 = __uint_as_float((uint32)u3); got |= 4u; }
                }
            } while (got != 7u);

            // deterministic order: own + peers in member order relative to g
            float pre = p + bs + v0 + v1 + v2;
            // tanh(x) = 1 - 2/(exp(2x)+1): exact identity, branch-free
            float e  = __expf(2.f * pre);
            float sn = 1.f - 2.f / (e + 1.f);
            sful[tid] = sn;                         // full s (local copy)
            int d = tid - 64 * g;
            if (d >= 0 && d < 64) aloc[128 + d] = sn;   // own s-quarter for next A
        }
        bar_lds();                                  // (2) s ready

        // ---- phase B: partial f[n] over this WG's n-quarter, k-quarter/thread ----
        float c0 = 0.f, c1 = 0.f;
        #pragma unroll
        for (int i = 0; i < 16; ++i) {
            float4 sv = s4[16 * h4 + i];            // wave-uniform LDS broadcast
            uint32 w0 = wB[2 * i], w1 = wB[2 * i + 1];
            c0 = fmaf(sv.x, lo16(w0), c0);
            c1 = fmaf(sv.y, hi16(w0), c1);
            c0 = fmaf(sv.z, lo16(w1), c0);
            c1 = fmaf(sv.w, hi16(w1), c1);
        }
        part[tid] = c0 + c1;
        bar_lds();                                  // (3) B partials visible

        if (tid < 128) {
            float f = part[tid] + part[tid + 128] + part[tid + 256] + part[tid + 384] + bo_r;
            f = fmaxf(f, 0.f);
            float xo = aloc[tid];
            float xn = (xo + 0.1f * f * Av_r) / (1.1f + 0.1f * f);
            aloc[tid] = xn;                         // own x-quarter for next A
            out[outBase + (size_t)t * 512 + tid] = xn;
        }
        if (tid < 32) aloc[192 + tid] = iv;         // stage I(t+1)
        bar_lds();                                  // (4) state ready for next A
    }
}

extern "C" void kernel_launch(void* const* d_in, const int* in_sizes, int n_in,
                              void* d_out, int out_size, void* d_ws, size_t ws_size,
                              hipStream_t stream)
{
    const float* I     = (const float*)d_in[0];
    const float* W_ih  = (const float*)d_in[1];
    const float* W_hh  = (const float*)d_in[2];
    const float* b_ih  = (const float*)d_in[3];
    const float* b_hh  = (const float*)d_in[4];
    const float* W_out = (const float*)d_in[5];
    const float* b_out = (const float*)d_in[6];
    const float* A     = (const float*)d_in[7];

    uint32* WREG = (uint32*)d_ws;
    uint64* exA  = (uint64*)((uint32*)d_ws + WREG_N);

    const int total = WREG_N + EXA_N;
    prep_kernel<<<(total + 1023) / 1024, 1024, 0, stream>>>(W_ih, W_hh, W_out, WREG, exA);
    scan_kernel<<<256, 512, 0, stream>>>(I, b_ih, b_hh, b_out, A,
                                         WREG, exA, (float*)d_out);
}